// Round 9
// baseline (177.351 us; speedup 1.0000x reference)
//
#include <hip/hip_runtime.h>
#include <hip/hip_fp16.h>

#define DIN 256
#define DOUT 64
#define SCAN_BLK 256
#define BUCKET_BITS 14
#define BUCKET (1 << BUCKET_BITS)   // 16384 nodes per bucket
#define CHUNKS 64
#define CAP 12500                   // max edges per (chunk,bucket) segment = chunk size
#define BM 128

using half8 = __attribute__((ext_vector_type(8))) _Float16;
using f32x4 = __attribute__((ext_vector_type(4))) float;

// ---------------- partition: split each chunk's edges into 4 dst-buckets (packed u32) ----------------
// Deterministic: per-thread contiguous ranges + packed block-scan; NO atomics.
__global__ __launch_bounds__(256) void part_kernel(
    const int* __restrict__ src, const int* __restrict__ dst,
    unsigned int* __restrict__ elist, int* __restrict__ gcnt, int n_edges)
{
    __shared__ unsigned int slo[256], shi[256];
    const int c = blockIdx.x;
    const int t = threadIdx.x;
    const int ebeg = (int)((long long)n_edges * c / CHUNKS);
    const int eend = (int)((long long)n_edges * (c + 1) / CHUNKS);
    const int len = eend - ebeg;
    const int tb = ebeg + (int)((long long)len * t / 256);
    const int te = ebeg + (int)((long long)len * (t + 1) / 256);

    // pass 1: per-thread bucket counts (registers only)
    int c0 = 0, c1 = 0, c2 = 0, c3 = 0;
    for (int e = tb; e < te; ++e) {
        int b = dst[e] >> BUCKET_BITS;
        c0 += (b == 0); c1 += (b == 1); c2 += (b == 2); c3 += (b == 3);
    }
    unsigned lo = (unsigned)c0 | ((unsigned)c1 << 16);   // fields <= 12500, no carry
    unsigned hi = (unsigned)c2 | ((unsigned)c3 << 16);
    slo[t] = lo; shi[t] = hi;
    __syncthreads();
    for (int off = 1; off < 256; off <<= 1) {
        unsigned ul = 0, uh = 0;
        if (t >= off) { ul = slo[t - off]; uh = shi[t - off]; }
        __syncthreads();
        if (t >= off) { slo[t] += ul; shi[t] += uh; }
        __syncthreads();
    }
    unsigned xlo = slo[t] - lo;   // exclusive prefix
    unsigned xhi = shi[t] - hi;
    if (t == 255) {
        unsigned tl = slo[255], th = shi[255];
        gcnt[c * 4 + 0] = (int)(tl & 0xffffu);
        gcnt[c * 4 + 1] = (int)(tl >> 16);
        gcnt[c * 4 + 2] = (int)(th & 0xffffu);
        gcnt[c * 4 + 3] = (int)(th >> 16);
    }
    int b0 = (int)(xlo & 0xffffu), b1 = (int)(xlo >> 16);
    int b2 = (int)(xhi & 0xffffu), b3 = (int)(xhi >> 16);
    unsigned int* e0 = elist + (size_t)(c * 4 + 0) * CAP;
    unsigned int* e1 = elist + (size_t)(c * 4 + 1) * CAP;
    unsigned int* e2 = elist + (size_t)(c * 4 + 2) * CAP;
    unsigned int* e3 = elist + (size_t)(c * 4 + 3) * CAP;
    // pass 2: re-read (L2-hot) and place packed edges
    for (int e = tb; e < te; ++e) {
        int d = dst[e];
        unsigned pk = ((unsigned)(d & (BUCKET - 1)) << 16) | (unsigned)src[e];
        int b = d >> BUCKET_BITS;
        if (b == 0)      e0[b0++] = pk;
        else if (b == 1) e1[b1++] = pk;
        else if (b == 2) e2[b2++] = pk;
        else             e3[b3++] = pk;
    }
}

// ---------------- histograms: z<4 -> dst-hist on dense segment; z>=4 -> src packed-pair hist ----------------
__global__ __launch_bounds__(256) void histB_kernel(
    const int* __restrict__ src, const unsigned int* __restrict__ elist,
    const int* __restrict__ gcnt, unsigned short* __restrict__ part_dst,
    unsigned short* __restrict__ part_src, int n_nodes, int n_edges, int n_pad)
{
    __shared__ unsigned int cnt[BUCKET];
    const int c = blockIdx.x, z = blockIdx.y;
    for (int i = threadIdx.x; i < BUCKET; i += 256) cnt[i] = 0;
    __syncthreads();

    if (z < 4) {
        const int b = z;
        const int len = gcnt[c * 4 + b];
        const unsigned int* seg = elist + (size_t)(c * 4 + b) * CAP;
        for (int e = threadIdx.x; e < len; e += 256)
            atomicAdd(&cnt[seg[e] >> 16], 1u);
        __syncthreads();
        unsigned short* row = part_dst + ((size_t)(b * CHUNKS + c) << BUCKET_BITS);
        for (int i = threadIdx.x; i < BUCKET; i += 256)
            row[i] = (unsigned short)cnt[i];
    } else {
        const int p = z - 4;            // pair 0: nodes 0..32767, pair 1: 32768..65535
        const int pairbase = p << 15;
        const int ebeg = (int)((long long)n_edges * c / CHUNKS);
        const int eend = (int)((long long)n_edges * (c + 1) / CHUNKS);
        const int nvec = (eend - ebeg) >> 2;
        const int4* s4 = (const int4*)(src + ebeg);
        for (int q = threadIdx.x; q < nvec; q += 256) {
            int4 e4 = s4[q];
            unsigned u0 = (unsigned)(e4.x - pairbase);
            unsigned u1 = (unsigned)(e4.y - pairbase);
            unsigned u2 = (unsigned)(e4.z - pairbase);
            unsigned u3 = (unsigned)(e4.w - pairbase);
            if (u0 < 32768u) atomicAdd(&cnt[u0 & (BUCKET - 1)], 1u << ((u0 >> BUCKET_BITS) << 4));
            if (u1 < 32768u) atomicAdd(&cnt[u1 & (BUCKET - 1)], 1u << ((u1 >> BUCKET_BITS) << 4));
            if (u2 < 32768u) atomicAdd(&cnt[u2 & (BUCKET - 1)], 1u << ((u2 >> BUCKET_BITS) << 4));
            if (u3 < 32768u) atomicAdd(&cnt[u3 & (BUCKET - 1)], 1u << ((u3 >> BUCKET_BITS) << 4));
        }
        for (int e = ebeg + (nvec << 2) + threadIdx.x; e < eend; e += 256) {
            unsigned u = (unsigned)(src[e] - pairbase);
            if (u < 32768u) atomicAdd(&cnt[u & (BUCKET - 1)], 1u << ((u >> BUCKET_BITS) << 4));
        }
        __syncthreads();
        unsigned short* row = part_src + (size_t)c * n_pad;
        for (int w = threadIdx.x; w < BUCKET; w += 256) {
            unsigned v = cnt[w];
            int n0 = pairbase + w;
            int n1 = pairbase + BUCKET + w;
            if (n0 < n_nodes) row[n0] = (unsigned short)(v & 0xffffu);
            if (n1 < n_nodes) row[n1] = (unsigned short)(v >> 16);
        }
    }
}

// ---------------- reduce: outdeg from part_src; in-place prefix over part_dst -> indeg, bsum; +convW ----------------
__global__ __launch_bounds__(256) void reduce_scan1_kernel(
    unsigned short* __restrict__ part_dst, const unsigned short* __restrict__ part_src,
    int* __restrict__ outdeg, int* __restrict__ indeg, int* __restrict__ bsum,
    int n_nodes, int n_pad, int nsb,
    const float* __restrict__ W, unsigned short* __restrict__ w16t)
{
    if (blockIdx.x >= nsb) {
        int idx = (blockIdx.x - nsb) * 256 + threadIdx.x;   // 0..16383
        int n = idx & 63, k = idx >> 6;
        __half v = __float2half(W[k * DOUT + n]);
        w16t[n * DIN + k] = *(unsigned short*)&v;
        return;
    }
    __shared__ int red[4];
    int i = blockIdx.x * 256 + threadIdx.x;
    int run = 0;
    if (i < n_nodes) {
        int s0 = 0;
        #pragma unroll
        for (int c = 0; c < CHUNKS; ++c) s0 += part_src[(size_t)c * n_pad + i];
        outdeg[i] = s0;
        const int b = i >> BUCKET_BITS, li = i & (BUCKET - 1);
        #pragma unroll
        for (int c = 0; c < CHUNKS; ++c) {
            size_t off = ((size_t)(b * CHUNKS + c) << BUCKET_BITS) + li;
            int t = part_dst[off];
            part_dst[off] = (unsigned short)run;
            run += t;
        }
        indeg[i] = run;
    }
    int v = run;
    #pragma unroll
    for (int off = 32; off >= 1; off >>= 1)
        v += __shfl_down(v, off, 64);
    if ((threadIdx.x & 63) == 0) red[threadIdx.x >> 6] = v;
    __syncthreads();
    if (threadIdx.x == 0)
        bsum[blockIdx.x] = red[0] + red[1] + red[2] + red[3];
}

// ---------------- emit rowptr; every block redundantly scans bsum in LDS ----------------
__global__ __launch_bounds__(SCAN_BLK) void emit_kernel(
    const int* __restrict__ indeg, const int* __restrict__ bsum,
    int* __restrict__ rowptr, int n, int n_edges, int nsb)
{
    __shared__ int bs[256];
    __shared__ int s[SCAN_BLK];
    int t = threadIdx.x;

    bs[t] = (t < nsb) ? bsum[t] : 0;
    __syncthreads();
    for (int off = 1; off < 256; off <<= 1) {
        int u = 0;
        if (t >= off) u = bs[t - off];
        __syncthreads();
        if (t >= off) bs[t] += u;
        __syncthreads();
    }
    int boff_blk = (blockIdx.x == 0) ? 0 : bs[blockIdx.x - 1];

    int idx = blockIdx.x * SCAN_BLK + t;
    int v = (idx < n) ? indeg[idx] : 0;
    s[t] = v;
    __syncthreads();
    for (int off = 1; off < SCAN_BLK; off <<= 1) {
        int u = 0;
        if (t >= off) u = s[t - off];
        __syncthreads();
        if (t >= off) s[t] += u;
        __syncthreads();
    }
    if (idx < n) rowptr[idx] = boff_blk + s[t] - v;
    if (idx == 0) rowptr[n] = n_edges;
}

// ---------------- CSR fill from dense segments via LDS cursors ----------------
__global__ __launch_bounds__(256) void fill_kernel(
    const unsigned int* __restrict__ elist, const int* __restrict__ gcnt,
    const unsigned short* __restrict__ part_dst, const int* __restrict__ rowptr,
    unsigned short* __restrict__ col, int n_nodes)
{
    __shared__ int cur[BUCKET];
    const int c = blockIdx.x, b = blockIdx.y;
    const int base = b << BUCKET_BITS;

    const unsigned short* prow = part_dst + ((size_t)(b * CHUNKS + c) << BUCKET_BITS);
    for (int i = threadIdx.x; i < BUCKET; i += 256) {
        int node = base + i;
        cur[i] = (node < n_nodes) ? rowptr[node] + (int)prow[i] : 0;
    }
    __syncthreads();

    const int len = gcnt[c * 4 + b];
    const unsigned int* seg = elist + (size_t)(c * 4 + b) * CAP;
    for (int e = threadIdx.x; e < len; e += 256) {
        unsigned v = seg[e];
        int pos = atomicAdd(&cur[v >> 16], 1);
        col[pos] = (unsigned short)(v & 0xffffu);
    }
}

// ---------------- MFMA GEMM: h (two fp16 column-planes) = (x * norm_src) @ W ----------------
__global__ __launch_bounds__(256) void gemm_mfma_kernel(
    const float* __restrict__ x, const unsigned short* __restrict__ w16t,
    const int* __restrict__ outdeg, __half* __restrict__ h,
    int n_nodes, size_t plane_elems)
{
    __shared__ unsigned char Abuf[BM * 128];   // [128 rows][64 halves = 128 B], swizzled
    __shared__ unsigned char Bbuf[64 * 512];   // [64 cols][256 halves = 512 B], swizzled

    const int tid = threadIdx.x;
    const int r0 = blockIdx.x * BM;
    const int w = tid >> 6;
    const int lane = tid & 63;
    const int l16 = lane & 15;
    const int kg = lane >> 4;

    {
        const uint4* srcB = (const uint4*)w16t;
        for (int u = tid; u < 64 * 32; u += 256) {
            int c = u >> 5, q = u & 31;
            uint4 v = srcB[u];
            int byte = (c << 9) + (q << 4);
            byte ^= ((c & 7) << 4);
            *(uint4*)(Bbuf + byte) = v;
        }
    }

    f32x4 acc[2][4] = {{{0.f,0.f,0.f,0.f}}};

    for (int k0 = 0; k0 < 4; ++k0) {
        if (k0) __syncthreads();
        for (int u = tid; u < BM * 16; u += 256) {
            int row = u >> 4, fq = u & 15;
            int grow = r0 + row;
            float4 v = make_float4(0.f, 0.f, 0.f, 0.f);
            if (grow < n_nodes)
                v = *(const float4*)(&x[(size_t)grow * DIN + (k0 << 6) + (fq << 2)]);
            __half2 p0 = __floats2half2_rn(v.x, v.y);
            __half2 p1 = __floats2half2_rn(v.z, v.w);
            uint2 wv;
            wv.x = *(unsigned int*)&p0;
            wv.y = *(unsigned int*)&p1;
            int byte = (row << 7) + (fq << 3);
            byte ^= ((row & 7) << 4);
            *(uint2*)(Abuf + byte) = wv;
        }
        __syncthreads();

        #pragma unroll
        for (int ks = 0; ks < 2; ++ks) {
            half8 a[2], b[4];
            #pragma unroll
            for (int rt = 0; rt < 2; ++rt) {
                int row = (w << 5) + (rt << 4) + l16;
                int byte = (row << 7) + (ks << 6) + (kg << 4);
                byte ^= ((row & 7) << 4);
                a[rt] = *(const half8*)(Abuf + byte);
            }
            #pragma unroll
            for (int ct = 0; ct < 4; ++ct) {
                int c = (ct << 4) + l16;
                int byte = (c << 9) + (k0 << 7) + (ks << 6) + (kg << 4);
                byte ^= ((c & 7) << 4);
                b[ct] = *(const half8*)(Bbuf + byte);
            }
            #pragma unroll
            for (int rt = 0; rt < 2; ++rt)
                #pragma unroll
                for (int ct = 0; ct < 4; ++ct)
                    acc[rt][ct] = __builtin_amdgcn_mfma_f32_16x16x32_f16(a[rt], b[ct], acc[rt][ct], 0, 0, 0);
        }
    }

    #pragma unroll
    for (int rt = 0; rt < 2; ++rt) {
        #pragma unroll
        for (int reg = 0; reg < 4; ++reg) {
            int grow = r0 + (w << 5) + (rt << 4) + (kg << 2) + reg;
            if (grow < n_nodes) {
                float ns = rsqrtf(fmaxf((float)outdeg[grow], 1.0f));
                #pragma unroll
                for (int ct = 0; ct < 4; ++ct) {
                    int colp = ((ct & 1) << 4) + l16;
                    __half* hp = h + (size_t)(ct >> 1) * plane_elems + ((size_t)grow << 5) + colp;
                    *hp = __float2half(acc[rt][ct][reg] * ns);
                }
            }
        }
    }
}

// ---------------- gather ONE 32-col plane (sequential launches keep plane L2-resident) ----------------
__global__ __launch_bounds__(256) void gather_kernel(
    const __half* __restrict__ h, const int* __restrict__ rowptr,
    const unsigned short* __restrict__ col, const float* __restrict__ bias,
    float* __restrict__ out, int n_nodes, size_t plane_elems, int plane)
{
    int wid = (blockIdx.x * blockDim.x + threadIdx.x) >> 6;
    int lane = threadIdx.x & 63;
    if (wid >= n_nodes) return;
    const int g = lane >> 3, l8 = lane & 7;

    const int beg = rowptr[wid];
    const int end = rowptr[wid + 1];
    const int deg = end - beg;

    const char* hbase = (const char*)(h + (size_t)plane * plane_elems) + (l8 << 3);

    float4 acc = make_float4(0.f, 0.f, 0.f, 0.f);
    #pragma unroll 2
    for (int i = beg + g; i < end; i += 8) {
        int s = col[i];
        uint2 v = *(const uint2*)(hbase + ((size_t)s << 6));
        __half2 p0 = *(__half2*)&v.x;
        __half2 p1 = *(__half2*)&v.y;
        float2 a = __half22float2(p0);
        float2 b2 = __half22float2(p1);
        acc.x += a.x; acc.y += a.y; acc.z += b2.x; acc.w += b2.y;
    }

    #pragma unroll
    for (int d = 8; d <= 32; d <<= 1) {
        acc.x += __shfl_xor(acc.x, d, 64);
        acc.y += __shfl_xor(acc.y, d, 64);
        acc.z += __shfl_xor(acc.z, d, 64);
        acc.w += __shfl_xor(acc.w, d, 64);
    }

    if (g == 0) {
        float nd = rsqrtf(fmaxf((float)deg, 1.0f));
        int c0 = (plane << 5) + (l8 << 2);
        float4 bb = *(const float4*)(&bias[c0]);
        float4 o;
        o.x = fmaxf(fmaf(acc.x, nd, bb.x), 0.f);
        o.y = fmaxf(fmaf(acc.y, nd, bb.y), 0.f);
        o.z = fmaxf(fmaf(acc.z, nd, bb.z), 0.f);
        o.w = fmaxf(fmaf(acc.w, nd, bb.w), 0.f);
        *(float4*)(&out[((size_t)wid << 6) + c0]) = o;
    }
}

extern "C" void kernel_launch(void* const* d_in, const int* in_sizes, int n_in,
                              void* d_out, int out_size, void* d_ws, size_t ws_size,
                              hipStream_t stream) {
    const float* x   = (const float*)d_in[0];
    const float* W   = (const float*)d_in[1];
    const float* b   = (const float*)d_in[2];
    const int*   src = (const int*)d_in[3];
    const int*   dst = (const int*)d_in[4];
    float* out = (float*)d_out;

    const int n_nodes = in_sizes[0] / DIN;   // 50000
    const int n_edges = in_sizes[3];         // 800000
    const int nsb = (n_nodes + SCAN_BLK - 1) / SCAN_BLK;         // 196
    const int n_pad = ((n_nodes + 63) / 64) * 64;                // 50048
    const size_t plane_elems = (size_t)n_pad * 32;               // halves per plane

    // workspace layout (no aliasing)
    int* outdeg = (int*)d_ws;                   // n
    int* indeg  = outdeg + n_nodes;             // n
    int* rowptr = indeg + n_nodes;              // n+1
    int* bsum   = rowptr + n_nodes + 1;         // 256
    int* gcnt   = bsum + 256;                   // 256 (CHUNKS*4)
    int* w16t_i = gcnt + 256;                   // 8192 ints = 16384 halves
    unsigned short* col = (unsigned short*)(w16t_i + 8192);          // n_edges u16
    size_t off = (size_t)((char*)col - (char*)d_ws) + (((size_t)n_edges * 2 + 63) / 64) * 64;
    unsigned int* elist = (unsigned int*)((char*)d_ws + off);        // CHUNKS*4*CAP u32 (12.8 MB)
    off += (((size_t)CHUNKS * 4 * CAP * 4 + 63) / 64) * 64;
    unsigned short* part_dst = (unsigned short*)((char*)d_ws + off); // 4*CHUNKS*16384 u16 (8 MB)
    off += (((size_t)4 * CHUNKS * BUCKET * 2 + 63) / 64) * 64;
    unsigned short* part_src = (unsigned short*)((char*)d_ws + off); // CHUNKS*n_pad u16 (6.4 MB)
    off += (((size_t)CHUNKS * n_pad * 2 + 63) / 64) * 64;
    __half* h = (__half*)((char*)d_ws + off);                        // 2 planes x n_pad x 32 (6.4 MB)
    unsigned short* w16t = (unsigned short*)w16t_i;

    part_kernel<<<CHUNKS, 256, 0, stream>>>(src, dst, elist, gcnt, n_edges);
    histB_kernel<<<dim3(CHUNKS, 6), 256, 0, stream>>>(src, elist, gcnt, part_dst, part_src, n_nodes, n_edges, n_pad);
    reduce_scan1_kernel<<<nsb + 64, 256, 0, stream>>>(part_dst, part_src, outdeg, indeg, bsum, n_nodes, n_pad, nsb, W, w16t);
    emit_kernel<<<nsb, SCAN_BLK, 0, stream>>>(indeg, bsum, rowptr, n_nodes, n_edges, nsb);
    fill_kernel<<<dim3(CHUNKS, 4), 256, 0, stream>>>(elist, gcnt, part_dst, rowptr, col, n_nodes);
    gemm_mfma_kernel<<<(n_nodes + BM - 1) / BM, 256, 0, stream>>>(x, w16t, outdeg, h, n_nodes, plane_elems);
    gather_kernel<<<((size_t)n_nodes * 64 + 255) / 256, 256, 0, stream>>>(h, rowptr, col, b, out, n_nodes, plane_elems, 0);
    gather_kernel<<<((size_t)n_nodes * 64 + 255) / 256, 256, 0, stream>>>(h, rowptr, col, b, out, n_nodes, plane_elems, 1);
}

// Round 10
// 113.890 us; speedup vs baseline: 1.5572x; 1.5572x over previous
//
#include <hip/hip_runtime.h>
#include <hip/hip_fp16.h>

#define DIN 256
#define DOUT 64
#define SCAN_BLK 256
#define BUCKET_BITS 14
#define BUCKET (1 << BUCKET_BITS)   // 16384-entry LDS word array; packs 2 buckets (32768 nodes)
#define CHUNKS 64
#define BM 128

using half8 = __attribute__((ext_vector_type(8))) _Float16;
using f32x4 = __attribute__((ext_vector_type(4))) float;

// ---------------- histogram: packed-pair LDS counters -> u16 partials ----------------
// grid = (CHUNKS, 2, 2): y = bucket-pair (nodes y*32768 .. +32767), z = array (0 src, 1 dst)
__global__ __launch_bounds__(256) void hist_kernel(
    const int* __restrict__ src, const int* __restrict__ dst,
    unsigned short* __restrict__ part, int n_nodes, int n_edges, int n_pad)
{
    __shared__ unsigned int cnt[BUCKET];
    const int c = blockIdx.x, p = blockIdx.y, a = blockIdx.z;
    const int* __restrict__ idx = a ? dst : src;
    const int pairbase = p << 15;

    for (int i = threadIdx.x; i < BUCKET; i += 256) cnt[i] = 0;
    __syncthreads();

    const int ebeg = (int)((long long)n_edges * c / CHUNKS);
    const int eend = (int)((long long)n_edges * (c + 1) / CHUNKS);
    const int nvec = (eend - ebeg) >> 2;
    const int4* idx4 = (const int4*)(idx + ebeg);
    for (int q = threadIdx.x; q < nvec; q += 256) {
        int4 e4 = idx4[q];
        unsigned u0 = (unsigned)(e4.x - pairbase);
        unsigned u1 = (unsigned)(e4.y - pairbase);
        unsigned u2 = (unsigned)(e4.z - pairbase);
        unsigned u3 = (unsigned)(e4.w - pairbase);
        if (u0 < 32768u) atomicAdd(&cnt[u0 & (BUCKET - 1)], 1u << ((u0 >> BUCKET_BITS) << 4));
        if (u1 < 32768u) atomicAdd(&cnt[u1 & (BUCKET - 1)], 1u << ((u1 >> BUCKET_BITS) << 4));
        if (u2 < 32768u) atomicAdd(&cnt[u2 & (BUCKET - 1)], 1u << ((u2 >> BUCKET_BITS) << 4));
        if (u3 < 32768u) atomicAdd(&cnt[u3 & (BUCKET - 1)], 1u << ((u3 >> BUCKET_BITS) << 4));
    }
    for (int e = ebeg + (nvec << 2) + threadIdx.x; e < eend; e += 256) {
        unsigned u = (unsigned)(idx[e] - pairbase);
        if (u < 32768u) atomicAdd(&cnt[u & (BUCKET - 1)], 1u << ((u >> BUCKET_BITS) << 4));
    }
    __syncthreads();

    unsigned short* row = part + (size_t)(a * CHUNKS + c) * n_pad;
    for (int w = threadIdx.x; w < BUCKET; w += 256) {
        unsigned v = cnt[w];
        int n0 = pairbase + w;
        int n1 = pairbase + BUCKET + w;
        if (n0 < n_nodes) row[n0] = (unsigned short)(v & 0xffffu);
        if (n1 < n_nodes) row[n1] = (unsigned short)(v >> 16);
    }
}

// ---------------- reduce partials -> outdeg/indeg, in-place prefix, bsum; extra blocks convert W ----------------
__global__ __launch_bounds__(256) void reduce_scan1_kernel(
    unsigned short* __restrict__ part, int* __restrict__ outdeg,
    int* __restrict__ indeg, int* __restrict__ bsum, int n_nodes, int n_pad,
    int nsb, const float* __restrict__ W, unsigned short* __restrict__ w16t)
{
    if (blockIdx.x >= nsb) {
        int idx = (blockIdx.x - nsb) * 256 + threadIdx.x;   // 0..16383
        int n = idx & 63, k = idx >> 6;
        __half v = __float2half(W[k * DOUT + n]);
        w16t[n * DIN + k] = *(unsigned short*)&v;
        return;
    }
    __shared__ int red[4];
    int i = blockIdx.x * 256 + threadIdx.x;
    int run = 0;
    if (i < n_nodes) {
        int s0 = 0;
        #pragma unroll
        for (int c = 0; c < CHUNKS; ++c) s0 += part[(size_t)c * n_pad + i];
        outdeg[i] = s0;
        #pragma unroll
        for (int c = 0; c < CHUNKS; ++c) {
            size_t off = (size_t)(CHUNKS + c) * n_pad + i;
            int t = part[off];
            part[off] = (unsigned short)run;
            run += t;
        }
        indeg[i] = run;
    }
    int v = run;
    #pragma unroll
    for (int off = 32; off >= 1; off >>= 1)
        v += __shfl_down(v, off, 64);
    if ((threadIdx.x & 63) == 0) red[threadIdx.x >> 6] = v;
    __syncthreads();
    if (threadIdx.x == 0)
        bsum[blockIdx.x] = red[0] + red[1] + red[2] + red[3];
}

// ---------------- emit rowptr; every block redundantly scans bsum in LDS ----------------
__global__ __launch_bounds__(SCAN_BLK) void emit_kernel(
    const int* __restrict__ indeg, const int* __restrict__ bsum,
    int* __restrict__ rowptr, int n, int n_edges, int nsb)
{
    __shared__ int bs[256];
    __shared__ int s[SCAN_BLK];
    int t = threadIdx.x;

    bs[t] = (t < nsb) ? bsum[t] : 0;
    __syncthreads();
    for (int off = 1; off < 256; off <<= 1) {
        int u = 0;
        if (t >= off) u = bs[t - off];
        __syncthreads();
        if (t >= off) bs[t] += u;
        __syncthreads();
    }
    int boff_blk = (blockIdx.x == 0) ? 0 : bs[blockIdx.x - 1];

    int idx = blockIdx.x * SCAN_BLK + t;
    int v = (idx < n) ? indeg[idx] : 0;
    s[t] = v;
    __syncthreads();
    for (int off = 1; off < SCAN_BLK; off <<= 1) {
        int u = 0;
        if (t >= off) u = s[t - off];
        __syncthreads();
        if (t >= off) s[t] += u;
        __syncthreads();
    }
    if (idx < n) rowptr[idx] = boff_blk + s[t] - v;
    if (idx == 0) rowptr[n] = n_edges;
}

// ---------------- CSR fill via LDS cursor multisplit (u16 col) ----------------
__global__ __launch_bounds__(256) void fill_kernel(
    const int* __restrict__ src, const int* __restrict__ dst,
    const unsigned short* __restrict__ part, const int* __restrict__ rowptr,
    unsigned short* __restrict__ col, int n_nodes, int n_edges, int n_pad)
{
    __shared__ int cur[BUCKET];
    const int c = blockIdx.x, b = blockIdx.y;
    const int base = b << BUCKET_BITS;
    const int lim = min(BUCKET, n_nodes - base);

    const unsigned short* prow = part + (size_t)(CHUNKS + c) * n_pad + base;
    const int* rp = rowptr + base;
    for (int i = threadIdx.x; i < lim; i += 256)
        cur[i] = rp[i] + (int)prow[i];
    __syncthreads();

    const int ebeg = (int)((long long)n_edges * c / CHUNKS);
    const int eend = (int)((long long)n_edges * (c + 1) / CHUNKS);
    const int nvec = (eend - ebeg) >> 2;
    const int4* dst4 = (const int4*)(dst + ebeg);
    const int4* src4 = (const int4*)(src + ebeg);
    for (int q = threadIdx.x; q < nvec; q += 256) {
        int4 d4 = dst4[q];
        int4 s4 = src4[q];
        unsigned v0 = (unsigned)(d4.x - base);
        unsigned v1 = (unsigned)(d4.y - base);
        unsigned v2 = (unsigned)(d4.z - base);
        unsigned v3 = (unsigned)(d4.w - base);
        if (v0 < (unsigned)BUCKET) col[atomicAdd(&cur[v0], 1)] = (unsigned short)s4.x;
        if (v1 < (unsigned)BUCKET) col[atomicAdd(&cur[v1], 1)] = (unsigned short)s4.y;
        if (v2 < (unsigned)BUCKET) col[atomicAdd(&cur[v2], 1)] = (unsigned short)s4.z;
        if (v3 < (unsigned)BUCKET) col[atomicAdd(&cur[v3], 1)] = (unsigned short)s4.w;
    }
    for (int e = ebeg + (nvec << 2) + threadIdx.x; e < eend; e += 256) {
        unsigned v = (unsigned)(dst[e] - base);
        if (v < (unsigned)BUCKET) col[atomicAdd(&cur[v], 1)] = (unsigned short)src[e];
    }
}

// ---------------- MFMA GEMM: h (two fp16 column-planes) = (x * norm_src) @ W ----------------
__global__ __launch_bounds__(256) void gemm_mfma_kernel(
    const float* __restrict__ x, const unsigned short* __restrict__ w16t,
    const int* __restrict__ outdeg, __half* __restrict__ h,
    int n_nodes, size_t plane_elems)
{
    __shared__ unsigned char Abuf[BM * 128];   // [128 rows][64 halves = 128 B], swizzled
    __shared__ unsigned char Bbuf[64 * 512];   // [64 cols][256 halves = 512 B], swizzled

    const int tid = threadIdx.x;
    const int r0 = blockIdx.x * BM;
    const int w = tid >> 6;
    const int lane = tid & 63;
    const int l16 = lane & 15;
    const int kg = lane >> 4;

    {
        const uint4* srcB = (const uint4*)w16t;
        for (int u = tid; u < 64 * 32; u += 256) {
            int c = u >> 5, q = u & 31;
            uint4 v = srcB[u];
            int byte = (c << 9) + (q << 4);
            byte ^= ((c & 7) << 4);
            *(uint4*)(Bbuf + byte) = v;
        }
    }

    f32x4 acc[2][4] = {{{0.f,0.f,0.f,0.f}}};

    for (int k0 = 0; k0 < 4; ++k0) {
        if (k0) __syncthreads();
        for (int u = tid; u < BM * 16; u += 256) {
            int row = u >> 4, fq = u & 15;
            int grow = r0 + row;
            float4 v = make_float4(0.f, 0.f, 0.f, 0.f);
            if (grow < n_nodes)
                v = *(const float4*)(&x[(size_t)grow * DIN + (k0 << 6) + (fq << 2)]);
            __half2 p0 = __floats2half2_rn(v.x, v.y);
            __half2 p1 = __floats2half2_rn(v.z, v.w);
            uint2 wv;
            wv.x = *(unsigned int*)&p0;
            wv.y = *(unsigned int*)&p1;
            int byte = (row << 7) + (fq << 3);
            byte ^= ((row & 7) << 4);
            *(uint2*)(Abuf + byte) = wv;
        }
        __syncthreads();

        #pragma unroll
        for (int ks = 0; ks < 2; ++ks) {
            half8 a[2], b[4];
            #pragma unroll
            for (int rt = 0; rt < 2; ++rt) {
                int row = (w << 5) + (rt << 4) + l16;
                int byte = (row << 7) + (ks << 6) + (kg << 4);
                byte ^= ((row & 7) << 4);
                a[rt] = *(const half8*)(Abuf + byte);
            }
            #pragma unroll
            for (int ct = 0; ct < 4; ++ct) {
                int c = (ct << 4) + l16;
                int byte = (c << 9) + (k0 << 7) + (ks << 6) + (kg << 4);
                byte ^= ((c & 7) << 4);
                b[ct] = *(const half8*)(Bbuf + byte);
            }
            #pragma unroll
            for (int rt = 0; rt < 2; ++rt)
                #pragma unroll
                for (int ct = 0; ct < 4; ++ct)
                    acc[rt][ct] = __builtin_amdgcn_mfma_f32_16x16x32_f16(a[rt], b[ct], acc[rt][ct], 0, 0, 0);
        }
    }

    #pragma unroll
    for (int rt = 0; rt < 2; ++rt) {
        #pragma unroll
        for (int reg = 0; reg < 4; ++reg) {
            int grow = r0 + (w << 5) + (rt << 4) + (kg << 2) + reg;
            if (grow < n_nodes) {
                float ns = rsqrtf(fmaxf((float)outdeg[grow], 1.0f));
                #pragma unroll
                for (int ct = 0; ct < 4; ++ct) {
                    int colp = ((ct & 1) << 4) + l16;
                    __half* hp = h + (size_t)(ct >> 1) * plane_elems + ((size_t)grow << 5) + colp;
                    *hp = __float2half(acc[rt][ct][reg] * ns);
                }
            }
        }
    }
}

// ---------------- gather ONE 32-col plane (sequential launches keep plane L2-resident) ----------------
__global__ __launch_bounds__(256) void gather_kernel(
    const __half* __restrict__ h, const int* __restrict__ rowptr,
    const unsigned short* __restrict__ col, const float* __restrict__ bias,
    float* __restrict__ out, int n_nodes, size_t plane_elems, int plane)
{
    int wid = (blockIdx.x * blockDim.x + threadIdx.x) >> 6;
    int lane = threadIdx.x & 63;
    if (wid >= n_nodes) return;
    const int g = lane >> 3, l8 = lane & 7;

    const int beg = rowptr[wid];
    const int end = rowptr[wid + 1];
    const int deg = end - beg;

    const char* hbase = (const char*)(h + (size_t)plane * plane_elems) + (l8 << 3);

    float4 acc = make_float4(0.f, 0.f, 0.f, 0.f);
    #pragma unroll 4
    for (int i = beg + g; i < end; i += 8) {
        int s = col[i];
        uint2 v = *(const uint2*)(hbase + ((size_t)s << 6));
        __half2 p0 = *(__half2*)&v.x;
        __half2 p1 = *(__half2*)&v.y;
        float2 a = __half22float2(p0);
        float2 b2 = __half22float2(p1);
        acc.x += a.x; acc.y += a.y; acc.z += b2.x; acc.w += b2.y;
    }

    #pragma unroll
    for (int d = 8; d <= 32; d <<= 1) {
        acc.x += __shfl_xor(acc.x, d, 64);
        acc.y += __shfl_xor(acc.y, d, 64);
        acc.z += __shfl_xor(acc.z, d, 64);
        acc.w += __shfl_xor(acc.w, d, 64);
    }

    if (g == 0) {
        float nd = rsqrtf(fmaxf((float)deg, 1.0f));
        int c0 = (plane << 5) + (l8 << 2);
        float4 bb = *(const float4*)(&bias[c0]);
        float4 o;
        o.x = fmaxf(fmaf(acc.x, nd, bb.x), 0.f);
        o.y = fmaxf(fmaf(acc.y, nd, bb.y), 0.f);
        o.z = fmaxf(fmaf(acc.z, nd, bb.z), 0.f);
        o.w = fmaxf(fmaf(acc.w, nd, bb.w), 0.f);
        *(float4*)(&out[((size_t)wid << 6) + c0]) = o;
    }
}

extern "C" void kernel_launch(void* const* d_in, const int* in_sizes, int n_in,
                              void* d_out, int out_size, void* d_ws, size_t ws_size,
                              hipStream_t stream) {
    const float* x   = (const float*)d_in[0];
    const float* W   = (const float*)d_in[1];
    const float* b   = (const float*)d_in[2];
    const int*   src = (const int*)d_in[3];
    const int*   dst = (const int*)d_in[4];
    float* out = (float*)d_out;

    const int n_nodes = in_sizes[0] / DIN;   // 50000
    const int n_edges = in_sizes[3];         // 800000
    const int nsb = (n_nodes + SCAN_BLK - 1) / SCAN_BLK;         // 196
    const int nbuck = (n_nodes + BUCKET - 1) >> BUCKET_BITS;     // 4
    const int npair = (nbuck + 1) >> 1;                          // 2 bucket-pairs
    const int n_pad = ((n_nodes + 63) / 64) * 64;                // 50048
    const size_t plane_elems = (size_t)n_pad * 32;               // halves per plane

    // workspace layout
    int* outdeg = (int*)d_ws;                   // n
    int* indeg  = outdeg + n_nodes;             // n
    int* rowptr = indeg + n_nodes;              // n+1
    int* bsum   = rowptr + n_nodes + 1;         // 256
    int* w16t_i = bsum + 256;                   // 8192 ints = 16384 halves
    unsigned short* col = (unsigned short*)(w16t_i + 8192);  // n_edges u16
    size_t col_bytes = ((size_t)n_edges * 2 + 63) / 64 * 64;
    size_t base = (size_t)((char*)col - (char*)d_ws) + col_bytes;
    unsigned short* part = (unsigned short*)((char*)d_ws + base);       // 2*CHUNKS*n_pad u16
    size_t h_off = base + ((size_t)2 * CHUNKS * n_pad * 2 + 63) / 64 * 64;
    __half* h = (__half*)((char*)d_ws + h_off);                         // 2 planes x n_pad x 32
    unsigned short* w16t = (unsigned short*)w16t_i;

    hist_kernel<<<dim3(CHUNKS, npair, 2), 256, 0, stream>>>(src, dst, part, n_nodes, n_edges, n_pad);
    reduce_scan1_kernel<<<nsb + 64, 256, 0, stream>>>(part, outdeg, indeg, bsum, n_nodes, n_pad, nsb, W, w16t);
    emit_kernel<<<nsb, SCAN_BLK, 0, stream>>>(indeg, bsum, rowptr, n_nodes, n_edges, nsb);
    fill_kernel<<<dim3(CHUNKS, nbuck), 256, 0, stream>>>(src, dst, part, rowptr, col, n_nodes, n_edges, n_pad);
    gemm_mfma_kernel<<<(n_nodes + BM - 1) / BM, 256, 0, stream>>>(x, w16t, outdeg, h, n_nodes, plane_elems);
    gather_kernel<<<((size_t)n_nodes * 64 + 255) / 256, 256, 0, stream>>>(h, rowptr, col, b, out, n_nodes, plane_elems, 0);
    gather_kernel<<<((size_t)n_nodes * 64 + 255) / 256, 256, 0, stream>>>(h, rowptr, col, b, out, n_nodes, plane_elems, 1);
}

// Round 11
// 107.647 us; speedup vs baseline: 1.6475x; 1.0580x over previous
//
#include <hip/hip_runtime.h>
#include <hip/hip_fp16.h>

#define DIN 256
#define DOUT 64
#define SCAN_BLK 256
#define BUCKET_BITS 14
#define BUCKET (1 << BUCKET_BITS)   // 16384-entry LDS word array; packs 2 buckets (32768 nodes)
#define CHUNKS 64
#define BM 128

using half8 = __attribute__((ext_vector_type(8))) _Float16;
using f32x4 = __attribute__((ext_vector_type(4))) float;

// ---------------- mega1: gemm role (blocks < gemm_blocks) || hist role (rest) ----------------
// gemm: h (two fp16 planes, UNNORMALIZED) = x @ W ; W converted f32->f16 in-block (L2-hot).
// hist: packed-pair LDS histograms of src/dst -> u16 partials.
__global__ __launch_bounds__(256) void mega1_kernel(
    const float* __restrict__ x, const float* __restrict__ W,
    const int* __restrict__ src, const int* __restrict__ dst,
    unsigned short* __restrict__ part, __half* __restrict__ h,
    int n_nodes, int n_edges, int n_pad, size_t plane_elems, int gemm_blocks)
{
    __shared__ unsigned char smem[65536];
    const int tid = threadIdx.x;

    if (blockIdx.x < gemm_blocks) {
        // ---------------- GEMM role ----------------
        unsigned char* Abuf = smem;            // [128 rows][128 B], swizzled (16 KB)
        unsigned char* Bbuf = smem + 16384;    // [64 cols][512 B], swizzled (32 KB)
        const int r0 = blockIdx.x * BM;
        const int w = tid >> 6;
        const int lane = tid & 63;
        const int l16 = lane & 15;
        const int kg = lane >> 4;

        // stage B from f32 W (coalesced: consecutive tid -> consecutive n)
        for (int idx = tid; idx < DIN * DOUT; idx += 256) {
            int k = idx >> 6, n = idx & 63;
            __half v = __float2half(W[idx]);
            int byte = (n << 9) + (k << 1);
            byte ^= ((n & 7) << 4);
            *(__half*)(Bbuf + byte) = v;
        }

        f32x4 acc[2][4] = {{{0.f,0.f,0.f,0.f}}};

        for (int k0 = 0; k0 < 4; ++k0) {
            if (k0) __syncthreads();
            for (int u = tid; u < BM * 16; u += 256) {
                int row = u >> 4, fq = u & 15;
                int grow = r0 + row;
                float4 v = make_float4(0.f, 0.f, 0.f, 0.f);
                if (grow < n_nodes)
                    v = *(const float4*)(&x[(size_t)grow * DIN + (k0 << 6) + (fq << 2)]);
                __half2 p0 = __floats2half2_rn(v.x, v.y);
                __half2 p1 = __floats2half2_rn(v.z, v.w);
                uint2 wv;
                wv.x = *(unsigned int*)&p0;
                wv.y = *(unsigned int*)&p1;
                int byte = (row << 7) + (fq << 3);
                byte ^= ((row & 7) << 4);
                *(uint2*)(Abuf + byte) = wv;
            }
            __syncthreads();   // covers A stage (and B stage on first pass)

            #pragma unroll
            for (int ks = 0; ks < 2; ++ks) {
                half8 a[2], b[4];
                #pragma unroll
                for (int rt = 0; rt < 2; ++rt) {
                    int row = (w << 5) + (rt << 4) + l16;
                    int byte = (row << 7) + (ks << 6) + (kg << 4);
                    byte ^= ((row & 7) << 4);
                    a[rt] = *(const half8*)(Abuf + byte);
                }
                #pragma unroll
                for (int ct = 0; ct < 4; ++ct) {
                    int c = (ct << 4) + l16;
                    int byte = (c << 9) + (k0 << 7) + (ks << 6) + (kg << 4);
                    byte ^= ((c & 7) << 4);
                    b[ct] = *(const half8*)(Bbuf + byte);
                }
                #pragma unroll
                for (int rt = 0; rt < 2; ++rt)
                    #pragma unroll
                    for (int ct = 0; ct < 4; ++ct)
                        acc[rt][ct] = __builtin_amdgcn_mfma_f32_16x16x32_f16(a[rt], b[ct], acc[rt][ct], 0, 0, 0);
            }
        }

        #pragma unroll
        for (int rt = 0; rt < 2; ++rt) {
            #pragma unroll
            for (int reg = 0; reg < 4; ++reg) {
                int grow = r0 + (w << 5) + (rt << 4) + (kg << 2) + reg;
                if (grow < n_nodes) {
                    #pragma unroll
                    for (int ct = 0; ct < 4; ++ct) {
                        int colp = ((ct & 1) << 4) + l16;
                        __half* hp = h + (size_t)(ct >> 1) * plane_elems + ((size_t)grow << 5) + colp;
                        *hp = __float2half(acc[rt][ct][reg]);
                    }
                }
            }
        }
    } else {
        // ---------------- HIST role ----------------
        unsigned int* cnt = (unsigned int*)smem;
        const int bid = blockIdx.x - gemm_blocks;   // 0..255
        const int c = bid & 63, p = (bid >> 6) & 1, a = bid >> 7;
        const int* __restrict__ idx = a ? dst : src;
        const int pairbase = p << 15;

        for (int i = tid; i < BUCKET; i += 256) cnt[i] = 0;
        __syncthreads();

        const int ebeg = (int)((long long)n_edges * c / CHUNKS);
        const int eend = (int)((long long)n_edges * (c + 1) / CHUNKS);
        const int nvec = (eend - ebeg) >> 2;
        const int4* idx4 = (const int4*)(idx + ebeg);
        for (int q = tid; q < nvec; q += 256) {
            int4 e4 = idx4[q];
            unsigned u0 = (unsigned)(e4.x - pairbase);
            unsigned u1 = (unsigned)(e4.y - pairbase);
            unsigned u2 = (unsigned)(e4.z - pairbase);
            unsigned u3 = (unsigned)(e4.w - pairbase);
            if (u0 < 32768u) atomicAdd(&cnt[u0 & (BUCKET - 1)], 1u << ((u0 >> BUCKET_BITS) << 4));
            if (u1 < 32768u) atomicAdd(&cnt[u1 & (BUCKET - 1)], 1u << ((u1 >> BUCKET_BITS) << 4));
            if (u2 < 32768u) atomicAdd(&cnt[u2 & (BUCKET - 1)], 1u << ((u2 >> BUCKET_BITS) << 4));
            if (u3 < 32768u) atomicAdd(&cnt[u3 & (BUCKET - 1)], 1u << ((u3 >> BUCKET_BITS) << 4));
        }
        for (int e = ebeg + (nvec << 2) + tid; e < eend; e += 256) {
            unsigned u = (unsigned)(idx[e] - pairbase);
            if (u < 32768u) atomicAdd(&cnt[u & (BUCKET - 1)], 1u << ((u >> BUCKET_BITS) << 4));
        }
        __syncthreads();

        unsigned short* row = part + (size_t)(a * CHUNKS + c) * n_pad;
        for (int w2 = tid; w2 < BUCKET; w2 += 256) {
            unsigned v = cnt[w2];
            int n0 = pairbase + w2;
            int n1 = pairbase + BUCKET + w2;
            if (n0 < n_nodes) row[n0] = (unsigned short)(v & 0xffffu);
            if (n1 < n_nodes) row[n1] = (unsigned short)(v >> 16);
        }
    }
}

// ---------------- reduce partials -> ns (f32 norm_src) / indeg, in-place prefix, bsum ----------------
__global__ __launch_bounds__(256) void reduce_scan1_kernel(
    unsigned short* __restrict__ part, float* __restrict__ nsf,
    int* __restrict__ indeg, int* __restrict__ bsum, int n_nodes, int n_pad)
{
    __shared__ int red[4];
    int i = blockIdx.x * 256 + threadIdx.x;
    int run = 0;
    if (i < n_nodes) {
        int s0 = 0;
        #pragma unroll
        for (int c = 0; c < CHUNKS; ++c) s0 += part[(size_t)c * n_pad + i];
        nsf[i] = rsqrtf(fmaxf((float)s0, 1.0f));
        #pragma unroll
        for (int c = 0; c < CHUNKS; ++c) {
            size_t off = (size_t)(CHUNKS + c) * n_pad + i;
            int t = part[off];
            part[off] = (unsigned short)run;
            run += t;
        }
        indeg[i] = run;
    }
    int v = run;
    #pragma unroll
    for (int off = 32; off >= 1; off >>= 1)
        v += __shfl_down(v, off, 64);
    if ((threadIdx.x & 63) == 0) red[threadIdx.x >> 6] = v;
    __syncthreads();
    if (threadIdx.x == 0)
        bsum[blockIdx.x] = red[0] + red[1] + red[2] + red[3];
}

// ---------------- emit rowptr; every block redundantly scans bsum in LDS ----------------
__global__ __launch_bounds__(SCAN_BLK) void emit_kernel(
    const int* __restrict__ indeg, const int* __restrict__ bsum,
    int* __restrict__ rowptr, int n, int n_edges, int nsb)
{
    __shared__ int bs[256];
    __shared__ int s[SCAN_BLK];
    int t = threadIdx.x;

    bs[t] = (t < nsb) ? bsum[t] : 0;
    __syncthreads();
    for (int off = 1; off < 256; off <<= 1) {
        int u = 0;
        if (t >= off) u = bs[t - off];
        __syncthreads();
        if (t >= off) bs[t] += u;
        __syncthreads();
    }
    int boff_blk = (blockIdx.x == 0) ? 0 : bs[blockIdx.x - 1];

    int idx = blockIdx.x * SCAN_BLK + t;
    int v = (idx < n) ? indeg[idx] : 0;
    s[t] = v;
    __syncthreads();
    for (int off = 1; off < SCAN_BLK; off <<= 1) {
        int u = 0;
        if (t >= off) u = s[t - off];
        __syncthreads();
        if (t >= off) s[t] += u;
        __syncthreads();
    }
    if (idx < n) rowptr[idx] = boff_blk + s[t] - v;
    if (idx == 0) rowptr[n] = n_edges;
}

// ---------------- CSR fill via LDS cursor multisplit (u16 col) ----------------
__global__ __launch_bounds__(256) void fill_kernel(
    const int* __restrict__ src, const int* __restrict__ dst,
    const unsigned short* __restrict__ part, const int* __restrict__ rowptr,
    unsigned short* __restrict__ col, int n_nodes, int n_edges, int n_pad)
{
    __shared__ int cur[BUCKET];
    const int c = blockIdx.x, b = blockIdx.y;
    const int base = b << BUCKET_BITS;
    const int lim = min(BUCKET, n_nodes - base);

    const unsigned short* prow = part + (size_t)(CHUNKS + c) * n_pad + base;
    const int* rp = rowptr + base;
    for (int i = threadIdx.x; i < lim; i += 256)
        cur[i] = rp[i] + (int)prow[i];
    __syncthreads();

    const int ebeg = (int)((long long)n_edges * c / CHUNKS);
    const int eend = (int)((long long)n_edges * (c + 1) / CHUNKS);
    const int nvec = (eend - ebeg) >> 2;
    const int4* dst4 = (const int4*)(dst + ebeg);
    const int4* src4 = (const int4*)(src + ebeg);
    for (int q = threadIdx.x; q < nvec; q += 256) {
        int4 d4 = dst4[q];
        int4 s4 = src4[q];
        unsigned v0 = (unsigned)(d4.x - base);
        unsigned v1 = (unsigned)(d4.y - base);
        unsigned v2 = (unsigned)(d4.z - base);
        unsigned v3 = (unsigned)(d4.w - base);
        if (v0 < (unsigned)BUCKET) col[atomicAdd(&cur[v0], 1)] = (unsigned short)s4.x;
        if (v1 < (unsigned)BUCKET) col[atomicAdd(&cur[v1], 1)] = (unsigned short)s4.y;
        if (v2 < (unsigned)BUCKET) col[atomicAdd(&cur[v2], 1)] = (unsigned short)s4.z;
        if (v3 < (unsigned)BUCKET) col[atomicAdd(&cur[v3], 1)] = (unsigned short)s4.w;
    }
    for (int e = ebeg + (nvec << 2) + threadIdx.x; e < eend; e += 256) {
        unsigned v = (unsigned)(dst[e] - base);
        if (v < (unsigned)BUCKET) col[atomicAdd(&cur[v], 1)] = (unsigned short)src[e];
    }
}

// ---------------- gather ONE 32-col plane; applies ns[src] per edge (fmac, free) ----------------
__global__ __launch_bounds__(256) void gather_kernel(
    const __half* __restrict__ h, const float* __restrict__ nsf,
    const int* __restrict__ rowptr, const unsigned short* __restrict__ col,
    const float* __restrict__ bias, float* __restrict__ out,
    int n_nodes, size_t plane_elems, int plane)
{
    int wid = (blockIdx.x * blockDim.x + threadIdx.x) >> 6;
    int lane = threadIdx.x & 63;
    if (wid >= n_nodes) return;
    const int g = lane >> 3, l8 = lane & 7;

    const int beg = rowptr[wid];
    const int end = rowptr[wid + 1];
    const int deg = end - beg;

    const char* hbase = (const char*)(h + (size_t)plane * plane_elems) + (l8 << 3);

    float4 acc = make_float4(0.f, 0.f, 0.f, 0.f);
    #pragma unroll 2
    for (int i = beg + g; i < end; i += 8) {
        int s = col[i];
        float ns = nsf[s];
        uint2 v = *(const uint2*)(hbase + ((size_t)s << 6));
        __half2 p0 = *(__half2*)&v.x;
        __half2 p1 = *(__half2*)&v.y;
        float2 a = __half22float2(p0);
        float2 b2 = __half22float2(p1);
        acc.x = fmaf(ns, a.x, acc.x);
        acc.y = fmaf(ns, a.y, acc.y);
        acc.z = fmaf(ns, b2.x, acc.z);
        acc.w = fmaf(ns, b2.y, acc.w);
    }

    #pragma unroll
    for (int d = 8; d <= 32; d <<= 1) {
        acc.x += __shfl_xor(acc.x, d, 64);
        acc.y += __shfl_xor(acc.y, d, 64);
        acc.z += __shfl_xor(acc.z, d, 64);
        acc.w += __shfl_xor(acc.w, d, 64);
    }

    if (g == 0) {
        float nd = rsqrtf(fmaxf((float)deg, 1.0f));
        int c0 = (plane << 5) + (l8 << 2);
        float4 bb = *(const float4*)(&bias[c0]);
        float4 o;
        o.x = fmaxf(fmaf(acc.x, nd, bb.x), 0.f);
        o.y = fmaxf(fmaf(acc.y, nd, bb.y), 0.f);
        o.z = fmaxf(fmaf(acc.z, nd, bb.z), 0.f);
        o.w = fmaxf(fmaf(acc.w, nd, bb.w), 0.f);
        *(float4*)(&out[((size_t)wid << 6) + c0]) = o;
    }
}

extern "C" void kernel_launch(void* const* d_in, const int* in_sizes, int n_in,
                              void* d_out, int out_size, void* d_ws, size_t ws_size,
                              hipStream_t stream) {
    const float* x   = (const float*)d_in[0];
    const float* W   = (const float*)d_in[1];
    const float* b   = (const float*)d_in[2];
    const int*   src = (const int*)d_in[3];
    const int*   dst = (const int*)d_in[4];
    float* out = (float*)d_out;

    const int n_nodes = in_sizes[0] / DIN;   // 50000
    const int n_edges = in_sizes[3];         // 800000
    const int nsb = (n_nodes + SCAN_BLK - 1) / SCAN_BLK;         // 196
    const int nbuck = (n_nodes + BUCKET - 1) >> BUCKET_BITS;     // 4
    const int n_pad = ((n_nodes + 63) / 64) * 64;                // 50048
    const size_t plane_elems = (size_t)n_pad * 32;               // halves per plane
    const int gemm_blocks = (n_nodes + BM - 1) / BM;             // 391

    // workspace layout
    float* nsf  = (float*)d_ws;                 // n (norm_src f32)
    int* indeg  = (int*)(nsf + n_nodes);        // n
    int* rowptr = indeg + n_nodes;              // n+1
    int* bsum   = rowptr + n_nodes + 1;         // 256
    unsigned short* col = (unsigned short*)(bsum + 256);   // n_edges u16
    size_t col_bytes = ((size_t)n_edges * 2 + 63) / 64 * 64;
    size_t base = (size_t)((char*)col - (char*)d_ws) + col_bytes;
    unsigned short* part = (unsigned short*)((char*)d_ws + base);       // 2*CHUNKS*n_pad u16
    size_t h_off = base + ((size_t)2 * CHUNKS * n_pad * 2 + 63) / 64 * 64;
    __half* h = (__half*)((char*)d_ws + h_off);                         // 2 planes x n_pad x 32

    mega1_kernel<<<gemm_blocks + 256, 256, 0, stream>>>(
        x, W, src, dst, part, h, n_nodes, n_edges, n_pad, plane_elems, gemm_blocks);
    reduce_scan1_kernel<<<nsb, 256, 0, stream>>>(part, nsf, indeg, bsum, n_nodes, n_pad);
    emit_kernel<<<nsb, SCAN_BLK, 0, stream>>>(indeg, bsum, rowptr, n_nodes, n_edges, nsb);
    fill_kernel<<<dim3(CHUNKS, nbuck), 256, 0, stream>>>(src, dst, part, rowptr, col, n_nodes, n_edges, n_pad);
    gather_kernel<<<((size_t)n_nodes * 64 + 255) / 256, 256, 0, stream>>>(h, nsf, rowptr, col, b, out, n_nodes, plane_elems, 0);
    gather_kernel<<<((size_t)n_nodes * 64 + 255) / 256, 256, 0, stream>>>(h, nsf, rowptr, col, b, out, n_nodes, plane_elems, 1);
}

// Round 12
// 106.619 us; speedup vs baseline: 1.6634x; 1.0096x over previous
//
#include <hip/hip_runtime.h>
#include <hip/hip_fp16.h>

#define DIN 256
#define DOUT 64
#define SCAN_BLK 256
#define BUCKET_BITS 14
#define BUCKET (1 << BUCKET_BITS)   // 16384 nodes per bucket; LDS word array packs 2 buckets
#define CHUNKS 64
#define BM 128

using half8 = __attribute__((ext_vector_type(8))) _Float16;
using f32x4 = __attribute__((ext_vector_type(4))) float;

// ---------------- histogram (packed-pair) + epack production ----------------
// grid = (CHUNKS, 2, 2): y = bucket-pair p, z = array a (0 src, 1 dst).
// a==1 blocks additionally write epack[e] = (dst<<16)|src for half their chunk (half p).
__global__ __launch_bounds__(256) void hist_kernel(
    const int* __restrict__ src, const int* __restrict__ dst,
    unsigned short* __restrict__ part, unsigned int* __restrict__ epack,
    int n_nodes, int n_edges, int n_pad)
{
    __shared__ unsigned int cnt[BUCKET];
    const int c = blockIdx.x, p = blockIdx.y, a = blockIdx.z;
    const int* __restrict__ idx = a ? dst : src;
    const int pairbase = p << 15;
    const int tid = threadIdx.x;

    for (int i = tid; i < BUCKET; i += 256) cnt[i] = 0;
    __syncthreads();

    const int ebeg = (int)((long long)n_edges * c / CHUNKS);
    const int eend = (int)((long long)n_edges * (c + 1) / CHUNKS);
    const int len = eend - ebeg;
    const int nvec = len >> 2;
    const int4* idx4 = (const int4*)(idx + ebeg);
    for (int q = tid; q < nvec; q += 256) {
        int4 e4 = idx4[q];
        unsigned u0 = (unsigned)(e4.x - pairbase);
        unsigned u1 = (unsigned)(e4.y - pairbase);
        unsigned u2 = (unsigned)(e4.z - pairbase);
        unsigned u3 = (unsigned)(e4.w - pairbase);
        if (u0 < 32768u) atomicAdd(&cnt[u0 & (BUCKET - 1)], 1u << ((u0 >> BUCKET_BITS) << 4));
        if (u1 < 32768u) atomicAdd(&cnt[u1 & (BUCKET - 1)], 1u << ((u1 >> BUCKET_BITS) << 4));
        if (u2 < 32768u) atomicAdd(&cnt[u2 & (BUCKET - 1)], 1u << ((u2 >> BUCKET_BITS) << 4));
        if (u3 < 32768u) atomicAdd(&cnt[u3 & (BUCKET - 1)], 1u << ((u3 >> BUCKET_BITS) << 4));
    }
    for (int e = ebeg + (nvec << 2) + tid; e < eend; e += 256) {
        unsigned u = (unsigned)(idx[e] - pairbase);
        if (u < 32768u) atomicAdd(&cnt[u & (BUCKET - 1)], 1u << ((u >> BUCKET_BITS) << 4));
    }

    // epack: dst-blocks pack half the chunk each (4-aligned split)
    if (a == 1) {
        const int half0 = ((len >> 1) + 3) & ~3;
        const int pb = ebeg + (p ? half0 : 0);
        const int pe = p ? eend : (ebeg + half0);
        const int nv2 = (pe - pb) >> 2;
        const int4* s4 = (const int4*)(src + pb);
        const int4* d4 = (const int4*)(dst + pb);
        uint4* o4 = (uint4*)(epack + pb);
        for (int q = tid; q < nv2; q += 256) {
            int4 s = s4[q];
            int4 d = d4[q];
            uint4 o;
            o.x = ((unsigned)d.x << 16) | (unsigned)s.x;
            o.y = ((unsigned)d.y << 16) | (unsigned)s.y;
            o.z = ((unsigned)d.z << 16) | (unsigned)s.z;
            o.w = ((unsigned)d.w << 16) | (unsigned)s.w;
            o4[q] = o;
        }
        for (int e = pb + (nv2 << 2) + tid; e < pe; e += 256)
            epack[e] = ((unsigned)dst[e] << 16) | (unsigned)src[e];
    }
    __syncthreads();

    unsigned short* row = part + (size_t)(a * CHUNKS + c) * n_pad;
    for (int w2 = tid; w2 < BUCKET; w2 += 256) {
        unsigned v = cnt[w2];
        int n0 = pairbase + w2;
        int n1 = pairbase + BUCKET + w2;
        if (n0 < n_nodes) row[n0] = (unsigned short)(v & 0xffffu);
        if (n1 < n_nodes) row[n1] = (unsigned short)(v >> 16);
    }
}

// ---------------- reduce partials -> nsf/indeg, in-place prefix, bsum; extra blocks convert W ----------------
__global__ __launch_bounds__(256) void reduce_scan1_kernel(
    unsigned short* __restrict__ part, float* __restrict__ nsf,
    int* __restrict__ indeg, int* __restrict__ bsum, int n_nodes, int n_pad,
    int nsb, const float* __restrict__ W, unsigned short* __restrict__ w16t)
{
    if (blockIdx.x >= nsb) {
        int idx = (blockIdx.x - nsb) * 256 + threadIdx.x;   // 0..16383
        int n = idx & 63, k = idx >> 6;
        __half v = __float2half(W[k * DOUT + n]);
        w16t[n * DIN + k] = *(unsigned short*)&v;
        return;
    }
    __shared__ int red[4];
    int i = blockIdx.x * 256 + threadIdx.x;
    int run = 0;
    if (i < n_nodes) {
        int s0 = 0;
        #pragma unroll
        for (int c = 0; c < CHUNKS; ++c) s0 += part[(size_t)c * n_pad + i];
        nsf[i] = rsqrtf(fmaxf((float)s0, 1.0f));
        #pragma unroll
        for (int c = 0; c < CHUNKS; ++c) {
            size_t off = (size_t)(CHUNKS + c) * n_pad + i;
            int t = part[off];
            part[off] = (unsigned short)run;
            run += t;
        }
        indeg[i] = run;
    }
    int v = run;
    #pragma unroll
    for (int off = 32; off >= 1; off >>= 1)
        v += __shfl_down(v, off, 64);
    if ((threadIdx.x & 63) == 0) red[threadIdx.x >> 6] = v;
    __syncthreads();
    if (threadIdx.x == 0)
        bsum[blockIdx.x] = red[0] + red[1] + red[2] + red[3];
}

// ---------------- emit rowptr; every block redundantly scans bsum in LDS ----------------
__global__ __launch_bounds__(SCAN_BLK) void emit_kernel(
    const int* __restrict__ indeg, const int* __restrict__ bsum,
    int* __restrict__ rowptr, int n, int n_edges, int nsb)
{
    __shared__ int bs[256];
    __shared__ int s[SCAN_BLK];
    int t = threadIdx.x;

    bs[t] = (t < nsb) ? bsum[t] : 0;
    __syncthreads();
    for (int off = 1; off < 256; off <<= 1) {
        int u = 0;
        if (t >= off) u = bs[t - off];
        __syncthreads();
        if (t >= off) bs[t] += u;
        __syncthreads();
    }
    int boff_blk = (blockIdx.x == 0) ? 0 : bs[blockIdx.x - 1];

    int idx = blockIdx.x * SCAN_BLK + t;
    int v = (idx < n) ? indeg[idx] : 0;
    s[t] = v;
    __syncthreads();
    for (int off = 1; off < SCAN_BLK; off <<= 1) {
        int u = 0;
        if (t >= off) u = s[t - off];
        __syncthreads();
        if (t >= off) s[t] += u;
        __syncthreads();
    }
    if (idx < n) rowptr[idx] = boff_blk + s[t] - v;
    if (idx == 0) rowptr[n] = n_edges;
}

// ---------------- CSR fill via LDS cursor multisplit, reading packed edges (4 B/edge) ----------------
__global__ __launch_bounds__(256) void fill_kernel(
    const unsigned int* __restrict__ epack,
    const unsigned short* __restrict__ part, const int* __restrict__ rowptr,
    unsigned short* __restrict__ col, int n_nodes, int n_edges, int n_pad)
{
    __shared__ int cur[BUCKET];
    const int c = blockIdx.x, b = blockIdx.y;
    const int base = b << BUCKET_BITS;
    const int lim = min(BUCKET, n_nodes - base);

    const unsigned short* prow = part + (size_t)(CHUNKS + c) * n_pad + base;
    const int* rp = rowptr + base;
    for (int i = threadIdx.x; i < lim; i += 256)
        cur[i] = rp[i] + (int)prow[i];
    __syncthreads();

    const int ebeg = (int)((long long)n_edges * c / CHUNKS);
    const int eend = (int)((long long)n_edges * (c + 1) / CHUNKS);
    const int nvec = (eend - ebeg) >> 2;
    const uint4* pk4 = (const uint4*)(epack + ebeg);
    for (int q = threadIdx.x; q < nvec; q += 256) {
        uint4 e4 = pk4[q];
        unsigned v0 = (e4.x >> 16) - (unsigned)base;
        unsigned v1 = (e4.y >> 16) - (unsigned)base;
        unsigned v2 = (e4.z >> 16) - (unsigned)base;
        unsigned v3 = (e4.w >> 16) - (unsigned)base;
        if (v0 < (unsigned)BUCKET) col[atomicAdd(&cur[v0], 1)] = (unsigned short)(e4.x & 0xffffu);
        if (v1 < (unsigned)BUCKET) col[atomicAdd(&cur[v1], 1)] = (unsigned short)(e4.y & 0xffffu);
        if (v2 < (unsigned)BUCKET) col[atomicAdd(&cur[v2], 1)] = (unsigned short)(e4.z & 0xffffu);
        if (v3 < (unsigned)BUCKET) col[atomicAdd(&cur[v3], 1)] = (unsigned short)(e4.w & 0xffffu);
    }
    for (int e = ebeg + (nvec << 2) + threadIdx.x; e < eend; e += 256) {
        unsigned pk = epack[e];
        unsigned v = (pk >> 16) - (unsigned)base;
        if (v < (unsigned)BUCKET) col[atomicAdd(&cur[v], 1)] = (unsigned short)(pk & 0xffffu);
    }
}

// ---------------- MFMA GEMM: h (two fp16 column-planes) = (x * norm_src) @ W ----------------
__global__ __launch_bounds__(256) void gemm_mfma_kernel(
    const float* __restrict__ x, const unsigned short* __restrict__ w16t,
    const float* __restrict__ nsf, __half* __restrict__ h,
    int n_nodes, size_t plane_elems)
{
    __shared__ unsigned char Abuf[BM * 128];   // [128 rows][64 halves = 128 B], swizzled
    __shared__ unsigned char Bbuf[64 * 512];   // [64 cols][256 halves = 512 B], swizzled

    const int tid = threadIdx.x;
    const int r0 = blockIdx.x * BM;
    const int w = tid >> 6;
    const int lane = tid & 63;
    const int l16 = lane & 15;
    const int kg = lane >> 4;

    {
        const uint4* srcB = (const uint4*)w16t;
        for (int u = tid; u < 64 * 32; u += 256) {
            int c = u >> 5, q = u & 31;
            uint4 v = srcB[u];
            int byte = (c << 9) + (q << 4);
            byte ^= ((c & 7) << 4);
            *(uint4*)(Bbuf + byte) = v;
        }
    }

    f32x4 acc[2][4] = {{{0.f,0.f,0.f,0.f}}};

    for (int k0 = 0; k0 < 4; ++k0) {
        if (k0) __syncthreads();
        for (int u = tid; u < BM * 16; u += 256) {
            int row = u >> 4, fq = u & 15;
            int grow = r0 + row;
            float4 v = make_float4(0.f, 0.f, 0.f, 0.f);
            if (grow < n_nodes)
                v = *(const float4*)(&x[(size_t)grow * DIN + (k0 << 6) + (fq << 2)]);
            __half2 p0 = __floats2half2_rn(v.x, v.y);
            __half2 p1 = __floats2half2_rn(v.z, v.w);
            uint2 wv;
            wv.x = *(unsigned int*)&p0;
            wv.y = *(unsigned int*)&p1;
            int byte = (row << 7) + (fq << 3);
            byte ^= ((row & 7) << 4);
            *(uint2*)(Abuf + byte) = wv;
        }
        __syncthreads();

        #pragma unroll
        for (int ks = 0; ks < 2; ++ks) {
            half8 a[2], b[4];
            #pragma unroll
            for (int rt = 0; rt < 2; ++rt) {
                int row = (w << 5) + (rt << 4) + l16;
                int byte = (row << 7) + (ks << 6) + (kg << 4);
                byte ^= ((row & 7) << 4);
                a[rt] = *(const half8*)(Abuf + byte);
            }
            #pragma unroll
            for (int ct = 0; ct < 4; ++ct) {
                int c = (ct << 4) + l16;
                int byte = (c << 9) + (k0 << 7) + (ks << 6) + (kg << 4);
                byte ^= ((c & 7) << 4);
                b[ct] = *(const half8*)(Bbuf + byte);
            }
            #pragma unroll
            for (int rt = 0; rt < 2; ++rt)
                #pragma unroll
                for (int ct = 0; ct < 4; ++ct)
                    acc[rt][ct] = __builtin_amdgcn_mfma_f32_16x16x32_f16(a[rt], b[ct], acc[rt][ct], 0, 0, 0);
        }
    }

    #pragma unroll
    for (int rt = 0; rt < 2; ++rt) {
        #pragma unroll
        for (int reg = 0; reg < 4; ++reg) {
            int grow = r0 + (w << 5) + (rt << 4) + (kg << 2) + reg;
            if (grow < n_nodes) {
                float ns = nsf[grow];
                #pragma unroll
                for (int ct = 0; ct < 4; ++ct) {
                    int colp = ((ct & 1) << 4) + l16;
                    __half* hp = h + (size_t)(ct >> 1) * plane_elems + ((size_t)grow << 5) + colp;
                    *hp = __float2half(acc[rt][ct][reg] * ns);
                }
            }
        }
    }
}

// ---------------- gather ONE 32-col plane (sequential launches keep plane L2-resident) ----------------
__global__ __launch_bounds__(256) void gather_kernel(
    const __half* __restrict__ h, const int* __restrict__ rowptr,
    const unsigned short* __restrict__ col, const float* __restrict__ bias,
    float* __restrict__ out, int n_nodes, size_t plane_elems, int plane)
{
    int wid = (blockIdx.x * blockDim.x + threadIdx.x) >> 6;
    int lane = threadIdx.x & 63;
    if (wid >= n_nodes) return;
    const int g = lane >> 3, l8 = lane & 7;

    const int beg = rowptr[wid];
    const int end = rowptr[wid + 1];
    const int deg = end - beg;

    const char* hbase = (const char*)(h + (size_t)plane * plane_elems) + (l8 << 3);

    float4 acc = make_float4(0.f, 0.f, 0.f, 0.f);
    #pragma unroll 2
    for (int i = beg + g; i < end; i += 8) {
        int s = col[i];
        uint2 v = *(const uint2*)(hbase + ((size_t)s << 6));
        __half2 p0 = *(__half2*)&v.x;
        __half2 p1 = *(__half2*)&v.y;
        float2 a = __half22float2(p0);
        float2 b2 = __half22float2(p1);
        acc.x += a.x; acc.y += a.y; acc.z += b2.x; acc.w += b2.y;
    }

    #pragma unroll
    for (int d = 8; d <= 32; d <<= 1) {
        acc.x += __shfl_xor(acc.x, d, 64);
        acc.y += __shfl_xor(acc.y, d, 64);
        acc.z += __shfl_xor(acc.z, d, 64);
        acc.w += __shfl_xor(acc.w, d, 64);
    }

    if (g == 0) {
        float nd = rsqrtf(fmaxf((float)deg, 1.0f));
        int c0 = (plane << 5) + (l8 << 2);
        float4 bb = *(const float4*)(&bias[c0]);
        float4 o;
        o.x = fmaxf(fmaf(acc.x, nd, bb.x), 0.f);
        o.y = fmaxf(fmaf(acc.y, nd, bb.y), 0.f);
        o.z = fmaxf(fmaf(acc.z, nd, bb.z), 0.f);
        o.w = fmaxf(fmaf(acc.w, nd, bb.w), 0.f);
        *(float4*)(&out[((size_t)wid << 6) + c0]) = o;
    }
}

extern "C" void kernel_launch(void* const* d_in, const int* in_sizes, int n_in,
                              void* d_out, int out_size, void* d_ws, size_t ws_size,
                              hipStream_t stream) {
    const float* x   = (const float*)d_in[0];
    const float* W   = (const float*)d_in[1];
    const float* b   = (const float*)d_in[2];
    const int*   src = (const int*)d_in[3];
    const int*   dst = (const int*)d_in[4];
    float* out = (float*)d_out;

    const int n_nodes = in_sizes[0] / DIN;   // 50000
    const int n_edges = in_sizes[3];         // 800000
    const int nsb = (n_nodes + SCAN_BLK - 1) / SCAN_BLK;         // 196
    const int nbuck = (n_nodes + BUCKET - 1) >> BUCKET_BITS;     // 4
    const int npair = (nbuck + 1) >> 1;                          // 2
    const int n_pad = ((n_nodes + 63) / 64) * 64;                // 50048
    const size_t plane_elems = (size_t)n_pad * 32;               // halves per plane

    // workspace layout
    float* nsf  = (float*)d_ws;                 // n
    int* indeg  = (int*)(nsf + n_nodes);        // n
    int* rowptr = indeg + n_nodes;              // n+1
    int* bsum   = rowptr + n_nodes + 1;         // 256
    unsigned short* w16t = (unsigned short*)(bsum + 256);    // 16384 u16
    size_t off = (size_t)((char*)(w16t + 16384) - (char*)d_ws);
    off = (off + 63) / 64 * 64;
    unsigned int* epack = (unsigned int*)((char*)d_ws + off);        // n_edges u32
    off += (((size_t)n_edges * 4 + 63) / 64) * 64;
    unsigned short* col = (unsigned short*)((char*)d_ws + off);      // n_edges u16
    off += (((size_t)n_edges * 2 + 63) / 64) * 64;
    unsigned short* part = (unsigned short*)((char*)d_ws + off);     // 2*CHUNKS*n_pad u16
    off += (((size_t)2 * CHUNKS * n_pad * 2 + 63) / 64) * 64;
    __half* h = (__half*)((char*)d_ws + off);                        // 2 planes x n_pad x 32

    hist_kernel<<<dim3(CHUNKS, npair, 2), 256, 0, stream>>>(src, dst, part, epack, n_nodes, n_edges, n_pad);
    reduce_scan1_kernel<<<nsb + 64, 256, 0, stream>>>(part, nsf, indeg, bsum, n_nodes, n_pad, nsb, W, w16t);
    emit_kernel<<<nsb, SCAN_BLK, 0, stream>>>(indeg, bsum, rowptr, n_nodes, n_edges, nsb);
    fill_kernel<<<dim3(CHUNKS, nbuck), 256, 0, stream>>>(epack, part, rowptr, col, n_nodes, n_edges, n_pad);
    gemm_mfma_kernel<<<(n_nodes + BM - 1) / BM, 256, 0, stream>>>(x, w16t, nsf, h, n_nodes, plane_elems);
    gather_kernel<<<((size_t)n_nodes * 64 + 255) / 256, 256, 0, stream>>>(h, rowptr, col, b, out, n_nodes, plane_elems, 0);
    gather_kernel<<<((size_t)n_nodes * 64 + 255) / 256, 256, 0, stream>>>(h, rowptr, col, b, out, n_nodes, plane_elems, 1);
}